// Round 5
// baseline (394.234 us; speedup 1.0000x reference)
//
#include <hip/hip_runtime.h>
#include <math.h>

// DynamicAttention1 — round 5: mega-kernel with MANUAL grid barrier.
// R4's hipLaunchCooperativeKernel silently failed at launch (absmax == max|ref|
// -> d_out untouched). Replace coop launch with a plain <<<512,256>>> launch
// and a hand-rolled device-scope barrier:
//   * __launch_bounds__(256,2) caps VGPR<=256 -> 2 blocks/CU guaranteed ->
//     all 512 blocks co-resident by construction (LDS 2x18KB << 160KB).
//   * One counter per phase boundary (4 total, 64B apart), zeroed by a 256B
//     hipMemsetAsync node each call (graph-capturable, no reset races).
//   * Arrive: fetch_add RELEASE/AGENT (publishes block's stores; the
//     compiler's pre-s_barrier waitcnt already drained all waves).
//     Wait: spin on ACQUIRE/AGENT load, bounded (no-hang failure mode).
// Phases (verbatim from verified R3 kernels, grid-stride over 512 blocks):
//   P0 prep: casts, weight transposes, keys & out bias-init
//   P1 keys split-K x4 (atomics) + q GEMM
//   P2 scores: factorized softmax marginals
//   P3 ctx -> bf16 into aout right half
//   P4 out split-K x2 (atomics into bias-pre-inited d_out)

typedef __attribute__((ext_vector_type(8))) short s16x8;
typedef __attribute__((ext_vector_type(4))) float f32x4;

#define NBLK 512u

__device__ __forceinline__ unsigned short f2bf(float f) {
    unsigned int u = __float_as_uint(f);
    return (unsigned short)((u + 0x7fffu + ((u >> 16) & 1u)) >> 16);  // RNE
}

// device-scope grid barrier; one dedicated pre-zeroed counter per use.
__device__ __forceinline__ void gbar(unsigned* cnt) {
    __syncthreads();   // drains every wave's memory ops (compiler waitcnt)
    if (threadIdx.x == 0) {
        __hip_atomic_fetch_add(cnt, 1u, __ATOMIC_RELEASE,
                               __HIP_MEMORY_SCOPE_AGENT);
        unsigned spins = 0;
        while (__hip_atomic_load(cnt, __ATOMIC_ACQUIRE,
                                 __HIP_MEMORY_SCOPE_AGENT) < NBLK &&
               ++spins < (8u << 20)) { }
    }
    __syncthreads();
}

struct MegaArgs {
    const float *query, *src, *trg, *Wq, *bq, *Ws, *bs, *Wo, *bo;
    unsigned short *qbf, *abf, *aout, *wqt, *wst, *wot;
    float *q, *keys, *wsT, *wtT, *out;
    unsigned *bar;
};

// ---- 64x64 tile MFMA GEMM, split-K partial via fp32 atomics ---------------
__device__ __forceinline__ void gemm64_atomic(
    const unsigned short* __restrict__ A, const unsigned short* __restrict__ BT,
    float* __restrict__ C, int m0, int n0, int K, int N, int kbase, int kiters,
    unsigned short* As, unsigned short* Bs) {
    const int t = threadIdx.x;
    const int lane = t & 63, wid = t >> 6;
    const int wm = (wid & 1) * 32, wn = (wid >> 1) * 32;
    const int lr = lane & 15, lq = lane >> 4;

    f32x4 acc[2][2] = {};
    for (int it = 0; it < kiters; it++) {
        const int kt = kbase + it * 64;
        __syncthreads();
#pragma unroll
        for (int i = 0; i < 2; i++) {
            const int idx = i * 256 + t, r = idx >> 3, c = idx & 7;
            *(s16x8*)&As[r * 72 + c * 8] =
                *(const s16x8*)(A + (size_t)(m0 + r) * K + kt + c * 8);
            *(s16x8*)&Bs[r * 72 + c * 8] =
                *(const s16x8*)(BT + (size_t)(n0 + r) * K + kt + c * 8);
        }
        __syncthreads();
#pragma unroll
        for (int s = 0; s < 2; s++) {
            s16x8 a0 = *(const s16x8*)&As[(wm + lr) * 72      + s * 32 + lq * 8];
            s16x8 a1 = *(const s16x8*)&As[(wm + 16 + lr) * 72 + s * 32 + lq * 8];
            s16x8 b0 = *(const s16x8*)&Bs[(wn + lr) * 72      + s * 32 + lq * 8];
            s16x8 b1 = *(const s16x8*)&Bs[(wn + 16 + lr) * 72 + s * 32 + lq * 8];
            acc[0][0] = __builtin_amdgcn_mfma_f32_16x16x32_bf16(a0, b0, acc[0][0], 0, 0, 0);
            acc[0][1] = __builtin_amdgcn_mfma_f32_16x16x32_bf16(a0, b1, acc[0][1], 0, 0, 0);
            acc[1][0] = __builtin_amdgcn_mfma_f32_16x16x32_bf16(a1, b0, acc[1][0], 0, 0, 0);
            acc[1][1] = __builtin_amdgcn_mfma_f32_16x16x32_bf16(a1, b1, acc[1][1], 0, 0, 0);
        }
    }
#pragma unroll
    for (int i = 0; i < 2; i++)
#pragma unroll
        for (int j = 0; j < 2; j++) {
            const int col = n0 + wn + j * 16 + lr;      // C/D: col=lane&15
            const int row = m0 + wm + i * 16 + lq * 4;  //      row=quad*4+reg
#pragma unroll
            for (int r = 0; r < 4; r++)
                unsafeAtomicAdd(&C[(size_t)(row + r) * N + col], acc[i][j][r]);
        }
}

// ---- 32x64 tile MFMA GEMM; direct+bias or split-K atomic epilogue ----------
template <bool ATOMIC>
__device__ __forceinline__ void gemm32(
    const unsigned short* __restrict__ A, const unsigned short* __restrict__ BT,
    const float* __restrict__ bias, float* __restrict__ C,
    int m0, int n0, int K, int N, int kbase, int kiters,
    unsigned short* As, unsigned short* Bs) {
    const int t = threadIdx.x;
    const int lane = t & 63, wid = t >> 6;
    const int wm = (wid & 1) * 16, wn = (wid >> 1) * 32;
    const int lr = lane & 15, lq = lane >> 4;

    f32x4 acc[2] = {};
    for (int it = 0; it < kiters; it++) {
        const int kt = kbase + it * 64;
        __syncthreads();
        {   // A: 32 rows
            const int r = t >> 3, c = t & 7;
            *(s16x8*)&As[r * 72 + c * 8] =
                *(const s16x8*)(A + (size_t)(m0 + r) * K + kt + c * 8);
        }
#pragma unroll
        for (int i = 0; i < 2; i++) {   // B: 64 rows
            const int idx = i * 256 + t, r = idx >> 3, c = idx & 7;
            *(s16x8*)&Bs[r * 72 + c * 8] =
                *(const s16x8*)(BT + (size_t)(n0 + r) * K + kt + c * 8);
        }
        __syncthreads();
#pragma unroll
        for (int s = 0; s < 2; s++) {
            s16x8 a0 = *(const s16x8*)&As[(wm + lr) * 72      + s * 32 + lq * 8];
            s16x8 b0 = *(const s16x8*)&Bs[(wn + lr) * 72      + s * 32 + lq * 8];
            s16x8 b1 = *(const s16x8*)&Bs[(wn + 16 + lr) * 72 + s * 32 + lq * 8];
            acc[0] = __builtin_amdgcn_mfma_f32_16x16x32_bf16(a0, b0, acc[0], 0, 0, 0);
            acc[1] = __builtin_amdgcn_mfma_f32_16x16x32_bf16(a0, b1, acc[1], 0, 0, 0);
        }
    }
#pragma unroll
    for (int j = 0; j < 2; j++) {
        const int col = n0 + wn + j * 16 + lr;
        const int row = m0 + wm + lq * 4;
        if (ATOMIC) {
#pragma unroll
            for (int r = 0; r < 4; r++)
                unsafeAtomicAdd(&C[(size_t)(row + r) * N + col], acc[j][r]);
        } else {
            const float bv = bias[col];
#pragma unroll
            for (int r = 0; r < 4; r++)
                C[(size_t)(row + r) * N + col] = acc[j][r] + bv;
        }
    }
}

// ---------------- the mega kernel -------------------------------------------
__global__ __launch_bounds__(256, 2) void k_mega(MegaArgs p) {
    __shared__ __align__(16) unsigned char smem[18432];
    unsigned short* As = (unsigned short*)smem;
    unsigned short* Bs = (unsigned short*)(smem + 9216);
    const int t = threadIdx.x;
    const int nb = gridDim.x;            // 512

    // ======== P0: prep — casts, weight transposes, bias inits ========
    for (int vb = blockIdx.x; vb < 6816; vb += nb) {
        if (vb < 3712) {                 // activation casts (float4 groups)
            const int idx = vb * 256 + t;
            if (idx < 131072) {
                float4 v = *(const float4*)(p.query + (size_t)idx * 4);
                ushort4 o = make_ushort4(f2bf(v.x), f2bf(v.y), f2bf(v.z), f2bf(v.w));
                *(ushort4*)(p.qbf + (size_t)idx * 4) = o;
                const int flat = idx * 4, m = flat >> 9, c = flat & 511;
                *(ushort4*)(p.aout + (size_t)m * 1024 + c) = o;
            } else if (idx < 540672) {
                const int i = idx - 131072;
                float4 v = *(const float4*)(p.src + (size_t)i * 4);
                *(ushort4*)(p.abf + (size_t)i * 4) =
                    make_ushort4(f2bf(v.x), f2bf(v.y), f2bf(v.z), f2bf(v.w));
            } else {
                const int i = idx - 540672;
                float4 v = *(const float4*)(p.trg + (size_t)i * 4);
                *(ushort4*)(p.abf + 1638400 + (size_t)i * 4) =
                    make_ushort4(f2bf(v.x), f2bf(v.y), f2bf(v.z), f2bf(v.w));
            }
        } else if (vb < 5504) {          // weight transpose-cast, 32x32 tiles
            float* tile = (float*)smem;  // [32][33]
            const int id = vb - 3712;
            const float* W; unsigned short* O; int K, tk, tn;
            if (id < 256)       { W = p.Wq; O = p.wqt; K = 512;  tk = id >> 4;          tn = id & 15; }
            else if (id < 1280) { W = p.Ws; O = p.wst; K = 2048; tk = (id - 256) >> 4;  tn = (id - 256) & 15; }
            else                { W = p.Wo; O = p.wot; K = 1024; tk = (id - 1280) >> 4; tn = (id - 1280) & 15; }
            const int row = t >> 3, c4 = (t & 7) * 4;
            float4 v = *(const float4*)(W + (size_t)(tk * 32 + row) * 512 + tn * 32 + c4);
            tile[row * 33 + c4 + 0] = v.x; tile[row * 33 + c4 + 1] = v.y;
            tile[row * 33 + c4 + 2] = v.z; tile[row * 33 + c4 + 3] = v.w;
            __syncthreads();
            ushort4 o = make_ushort4(
                f2bf(tile[(c4 + 0) * 33 + row]), f2bf(tile[(c4 + 1) * 33 + row]),
                f2bf(tile[(c4 + 2) * 33 + row]), f2bf(tile[(c4 + 3) * 33 + row]));
            *(ushort4*)(O + (size_t)(tn * 32 + row) * K + tk * 32 + c4) = o;
            __syncthreads();             // tile reused by next vb iteration
        } else if (vb < 6304) {          // keys = broadcast bs (split-K base)
            const int f = ((vb - 5504) * 256 + t) * 4;
            *(float4*)(p.keys + f) = *(const float4*)(p.bs + (f & 511));
        } else {                         // out = broadcast bo (split-K base)
            const int f = ((vb - 6304) * 256 + t) * 4;
            *(float4*)(p.out + f) = *(const float4*)(p.bo + (f & 511));
        }
    }
    gbar(p.bar + 0);

    // ======== P1: keys split-K x4 (atomic) + q GEMM ========
    for (int vb = blockIdx.x; vb < 1056; vb += nb) {
        if (vb < 800) {
            const int c = vb / 200, rem = vb % 200;
            const int mt = rem >> 3, nt = rem & 7;
            gemm64_atomic(p.abf, p.wst, p.keys, mt * 64, nt * 64, 2048, 512,
                          c * 512, 8, As, Bs);
        } else {
            const int r = vb - 800;
            const int mt = r >> 3, nt = r & 7;
            gemm32<false>(p.qbf, p.wqt, p.bq, p.q, mt * 32, nt * 64, 512, 512,
                          0, 8, As, Bs);
        }
    }
    gbar(p.bar + 16);

    // ======== P2: scores + factorized softmax ========
    {
        float* qsh = (float*)smem;               // 512 floats
        float* sc  = (float*)(smem + 2048);      // 200 floats
        const int wave = t >> 6, lane = t & 63;
        for (int vb = blockIdx.x; vb < 1024; vb += nb) {
            const int b = vb >> 7, l = vb & 127;
            if (t < 128)
                *(float4*)&qsh[t * 4] =
                    *(const float4*)(p.q + (size_t)vb * 512 + t * 4);
            __syncthreads();
            const float4* qp = (const float4*)qsh;
            const float4 qv1 = qp[lane], qv2 = qp[lane + 64];

            for (int idx = wave; idx < 200; idx += 4) {
                const int kr = (idx < 100) ? (b * 100 + idx)
                                           : (800 + b * 100 + (idx - 100));
                const float4* kp = (const float4*)(p.keys + (size_t)kr * 512);
                const float4 kv1 = kp[lane], kv2 = kp[lane + 64];
                float d = kv1.x * qv1.x + kv1.y * qv1.y + kv1.z * qv1.z + kv1.w * qv1.w
                        + kv2.x * qv2.x + kv2.y * qv2.y + kv2.z * qv2.z + kv2.w * qv2.w;
#pragma unroll
                for (int off = 32; off > 0; off >>= 1) d += __shfl_down(d, off);
                if (lane == 0)
                    sc[idx] = ((idx < 100) ? d : -d) * (1.0f / 32.0f);
            }
            __syncthreads();

            if (wave < 2) {
                const float* sp = sc + wave * 100;
                const bool hi = (lane + 64) < 100;
                const float v0 = sp[lane];
                const float v1 = hi ? sp[lane + 64] : -INFINITY;
                float mx = fmaxf(v0, v1);
#pragma unroll
                for (int off = 32; off > 0; off >>= 1) mx = fmaxf(mx, __shfl_xor(mx, off));
                const float e0 = __expf(v0 - mx);
                const float e1 = hi ? __expf(v1 - mx) : 0.f;
                float s = e0 + e1;
#pragma unroll
                for (int off = 32; off > 0; off >>= 1) s += __shfl_xor(s, off);
                const float inv = 1.f / s;
                float* op = (wave == 0) ? p.wsT : p.wtT;
                op[(b * 100 + lane) * 128 + l] = e0 * inv;
                if (hi) op[(b * 100 + lane + 64) * 128 + l] = e1 * inv;
            }
            __syncthreads();             // sc/qsh reused by next vb
        }
    }
    gbar(p.bar + 32);

    // ======== P3: ctx -> bf16 into aout cols 512..1023 ========
    {
        float* cAs = (float*)smem;               // [40][64]
        float* cBs = (float*)(smem + 10240);     // [40][32]
        const int tx = t & 7, ty = t >> 3;       // tx: n/4, ty: l/2
        for (int vb = blockIdx.x; vb < 256; vb += nb) {
            const int n0 = (vb & 15) * 32;
            const int b  = (vb >> 4) & 7;
            const int l0 = (vb >> 7) * 64;
            float acc[2][4] = {};
            for (int c5 = 0; c5 < 5; c5++) {
                const int kbase = c5 * 40;
                __syncthreads();
#pragma unroll
                for (int e = 0; e < 10; e++) {
                    const int idx = t + e * 256;
                    const int k = idx >> 6, j = idx & 63;
                    const int kk = kbase + k;
                    cAs[k * 64 + j] = (kk < 100)
                        ? p.wsT[(b * 100 + kk) * 128 + l0 + j]
                        : p.wtT[(b * 100 + (kk - 100)) * 128 + l0 + j];
                }
#pragma unroll
                for (int e = 0; e < 5; e++) {
                    const int idx = t + e * 256;
                    const int k = idx >> 5, j = idx & 31;
                    const int kk = kbase + k;
                    cBs[k * 32 + j] = (kk < 100)
                        ?  p.keys[(size_t)(b * 100 + kk) * 512 + n0 + j]
                        : -p.keys[(size_t)(800 + b * 100 + (kk - 100)) * 512 + n0 + j];
                }
                __syncthreads();
#pragma unroll 8
                for (int k = 0; k < 40; k++) {
                    float ar0 = cAs[k * 64 + ty * 2], ar1 = cAs[k * 64 + ty * 2 + 1];
                    float br[4];
                    *(float4*)br = *(const float4*)&cBs[k * 32 + tx * 4];
#pragma unroll
                    for (int j = 0; j < 4; j++) {
                        acc[0][j] = fmaf(ar0, br[j], acc[0][j]);
                        acc[1][j] = fmaf(ar1, br[j], acc[1][j]);
                    }
                }
            }
            const float s2 = 0.70710678118654752f;
#pragma unroll
            for (int i = 0; i < 2; i++) {
                const int m = b * 128 + l0 + ty * 2 + i;
                ushort4 o = make_ushort4(f2bf(acc[i][0] * s2), f2bf(acc[i][1] * s2),
                                         f2bf(acc[i][2] * s2), f2bf(acc[i][3] * s2));
                *(ushort4*)(p.aout + (size_t)m * 1024 + 512 + n0 + tx * 4) = o;
            }
        }
    }
    gbar(p.bar + 48);

    // ======== P4: out split-K x2 (atomic into bo-pre-inited d_out) ========
    for (int vb = blockIdx.x; vb < 512; vb += nb) {
        const int c = vb >> 8, rem = vb & 255;
        const int mt = rem >> 3, nt = rem & 7;
        gemm32<true>(p.aout, p.wot, nullptr, p.out, mt * 32, nt * 64, 1024, 512,
                     c * 512, 8, As, Bs);
    }
}

// ---------------- launch ----------------------------------------------------
extern "C" void kernel_launch(void* const* d_in, const int* in_sizes, int n_in,
                              void* d_out, int out_size, void* d_ws, size_t ws_size,
                              hipStream_t stream) {
    MegaArgs a;
    a.query = (const float*)d_in[0];
    a.src   = (const float*)d_in[1];
    a.trg   = (const float*)d_in[2];
    a.Wq    = (const float*)d_in[3];
    a.bq    = (const float*)d_in[4];
    a.Ws    = (const float*)d_in[5];
    a.bs    = (const float*)d_in[6];
    a.Wo    = (const float*)d_in[7];
    a.bo    = (const float*)d_in[8];
    a.out   = (float*)d_out;

    float* q    = (float*)d_ws;               // 1024*512
    float* keys = q    + 524288;              // 1600*512
    float* wsT  = keys + 819200;              // 8*100*128
    float* wtT  = wsT  + 102400;
    unsigned short* qbf = (unsigned short*)(wtT + 102400);
    unsigned short* abf = qbf + 524288;       // [src;trg] 1600x2048
    unsigned short* aout= abf + 3276800;      // [query,ctx] 1024x1024
    unsigned short* wqt = aout + 1048576;     // WqT 512x512
    unsigned short* wst = wqt  + 262144;      // WsT 512x2048
    unsigned short* wot = wst  + 1048576;     // WoT 512x1024
    unsigned* bar = (unsigned*)(wot + 524288);// 4 counters, 64B apart (256 B)

    a.q = q; a.keys = keys; a.wsT = wsT; a.wtT = wtT;
    a.qbf = qbf; a.abf = abf; a.aout = aout;
    a.wqt = wqt; a.wst = wst; a.wot = wot;
    a.bar = bar;

    hipMemsetAsync(bar, 0, 256, stream);      // graph-capturable memset node
    k_mega<<<dim3(NBLK), dim3(256), 0, stream>>>(a);
}

// Round 6
// 150.415 us; speedup vs baseline: 2.6210x; 2.6210x over previous
//
#include <hip/hip_runtime.h>
#include <math.h>

// DynamicAttention1 — round 6: revert to 5-kernel structure (R4/R5 mega-kernel
// regressed: phases under grid barriers ran at 8 waves/CU with whole-GPU idle
// at each barrier -> 338us kernel). R5 also showed fixed per-call overhead is
// only ~56us, so R3's kernels consumed ~100us -> attack latency exposure:
//   * register prefetch double-buffer in all GEMM K-loops (global loads for
//     iter i+1 issued before MFMA of iter i)
//   * out GEMM split-K x2 (512 blocks) w/ atomics, bias pre-init in prep
//   * ctx: 512 blocks (32x32 tiles) + prefetch
// Launches: prep -> stageB(keys splitKx4 + q) -> scores -> ctx -> out

typedef __attribute__((ext_vector_type(8))) short s16x8;
typedef __attribute__((ext_vector_type(4))) float f32x4;

__device__ __forceinline__ unsigned short f2bf(float f) {
    unsigned int u = __float_as_uint(f);
    return (unsigned short)((u + 0x7fffu + ((u >> 16) & 1u)) >> 16);  // RNE
}

// ---------------- prep: casts + weight transposes + bias inits --------------
__global__ __launch_bounds__(256) void k_prep(
    const float* __restrict__ query, const float* __restrict__ src,
    const float* __restrict__ trg, const float* __restrict__ Wq,
    const float* __restrict__ Ws, const float* __restrict__ Wo,
    const float* __restrict__ bs, const float* __restrict__ bo,
    unsigned short* __restrict__ qbf, unsigned short* __restrict__ aout,
    unsigned short* __restrict__ abf, unsigned short* __restrict__ WqT,
    unsigned short* __restrict__ WsT, unsigned short* __restrict__ WoT,
    float* __restrict__ keys, float* __restrict__ out) {
    __shared__ float tile[32][33];
    const int bid = blockIdx.x, t = threadIdx.x;

    if (bid < 3712) {                       // activation casts (float4 groups)
        const int idx = bid * 256 + t;
        if (idx < 131072) {
            float4 v = *(const float4*)(query + (size_t)idx * 4);
            ushort4 o = make_ushort4(f2bf(v.x), f2bf(v.y), f2bf(v.z), f2bf(v.w));
            *(ushort4*)(qbf + (size_t)idx * 4) = o;
            const int flat = idx * 4, m = flat >> 9, c = flat & 511;
            *(ushort4*)(aout + (size_t)m * 1024 + c) = o;   // A_out left half
        } else if (idx < 540672) {
            const int i = idx - 131072;
            float4 v = *(const float4*)(src + (size_t)i * 4);
            *(ushort4*)(abf + (size_t)i * 4) =
                make_ushort4(f2bf(v.x), f2bf(v.y), f2bf(v.z), f2bf(v.w));
        } else {
            const int i = idx - 540672;
            float4 v = *(const float4*)(trg + (size_t)i * 4);
            *(ushort4*)(abf + 1638400 + (size_t)i * 4) =
                make_ushort4(f2bf(v.x), f2bf(v.y), f2bf(v.z), f2bf(v.w));
        }
    } else if (bid < 5504) {                // weight transpose-cast, 32x32 tiles
        const int id = bid - 3712;
        const float* W; unsigned short* O; int K, tk, tn;
        if (id < 256)       { W = Wq; O = WqT; K = 512;  tk = id >> 4;          tn = id & 15; }
        else if (id < 1280) { W = Ws; O = WsT; K = 2048; tk = (id - 256) >> 4;  tn = (id - 256) & 15; }
        else                { W = Wo; O = WoT; K = 1024; tk = (id - 1280) >> 4; tn = (id - 1280) & 15; }
        const int row = t >> 3, c4 = (t & 7) * 4;
        float4 v = *(const float4*)(W + (size_t)(tk * 32 + row) * 512 + tn * 32 + c4);
        tile[row][c4 + 0] = v.x; tile[row][c4 + 1] = v.y;
        tile[row][c4 + 2] = v.z; tile[row][c4 + 3] = v.w;
        __syncthreads();
        ushort4 o = make_ushort4(f2bf(tile[c4 + 0][row]), f2bf(tile[c4 + 1][row]),
                                 f2bf(tile[c4 + 2][row]), f2bf(tile[c4 + 3][row]));
        *(ushort4*)(O + (size_t)(tn * 32 + row) * K + tk * 32 + c4) = o;
    } else if (bid < 6304) {                // keys = broadcast bs (split-K base)
        const int f = ((bid - 5504) * 256 + t) * 4;
        *(float4*)(keys + f) = *(const float4*)(bs + (f & 511));
    } else {                                // out = broadcast bo (split-K base)
        const int f = ((bid - 6304) * 256 + t) * 4;
        *(float4*)(out + f) = *(const float4*)(bo + (f & 511));
    }
}

// ---------------- MFMA GEMM bodies (register-prefetch pipelined) ------------
// A [M][K] bf16, BT [N][K] bf16. LDS rows padded to 72 bf16 (144 B).

// 64x64 tile, 4 waves 2x2; split-K partial accumulated via fp32 atomics.
__device__ __forceinline__ void gemm64_atomic(
    const unsigned short* __restrict__ A, const unsigned short* __restrict__ BT,
    float* __restrict__ C, int m0, int n0, int K, int N, int kbase, int kiters,
    unsigned short* As, unsigned short* Bs) {
    const int t = threadIdx.x;
    const int lane = t & 63, wid = t >> 6;
    const int wm = (wid & 1) * 32, wn = (wid >> 1) * 32;
    const int lr = lane & 15, lq = lane >> 4;
    const int r = t >> 3, c8 = (t & 7) * 8;       // staging coords

    s16x8 ra0, ra1, rb0, rb1;
#define LD64(kt)                                                           \
    ra0 = *(const s16x8*)(A  + (size_t)(m0 + r)      * K + (kt) + c8);     \
    ra1 = *(const s16x8*)(A  + (size_t)(m0 + r + 32) * K + (kt) + c8);     \
    rb0 = *(const s16x8*)(BT + (size_t)(n0 + r)      * K + (kt) + c8);     \
    rb1 = *(const s16x8*)(BT + (size_t)(n0 + r + 32) * K + (kt) + c8);

    f32x4 acc[2][2] = {};
    LD64(kbase);
    for (int it = 0; it < kiters; it++) {
        __syncthreads();                   // previous tile fully consumed
        *(s16x8*)&As[r * 72 + c8]        = ra0;
        *(s16x8*)&As[(r + 32) * 72 + c8] = ra1;
        *(s16x8*)&Bs[r * 72 + c8]        = rb0;
        *(s16x8*)&Bs[(r + 32) * 72 + c8] = rb1;
        __syncthreads();
        if (it + 1 < kiters) { LD64(kbase + (it + 1) * 64); }  // prefetch
#pragma unroll
        for (int s = 0; s < 2; s++) {
            s16x8 a0 = *(const s16x8*)&As[(wm + lr) * 72      + s * 32 + lq * 8];
            s16x8 a1 = *(const s16x8*)&As[(wm + 16 + lr) * 72 + s * 32 + lq * 8];
            s16x8 b0 = *(const s16x8*)&Bs[(wn + lr) * 72      + s * 32 + lq * 8];
            s16x8 b1 = *(const s16x8*)&Bs[(wn + 16 + lr) * 72 + s * 32 + lq * 8];
            acc[0][0] = __builtin_amdgcn_mfma_f32_16x16x32_bf16(a0, b0, acc[0][0], 0, 0, 0);
            acc[0][1] = __builtin_amdgcn_mfma_f32_16x16x32_bf16(a0, b1, acc[0][1], 0, 0, 0);
            acc[1][0] = __builtin_amdgcn_mfma_f32_16x16x32_bf16(a1, b0, acc[1][0], 0, 0, 0);
            acc[1][1] = __builtin_amdgcn_mfma_f32_16x16x32_bf16(a1, b1, acc[1][1], 0, 0, 0);
        }
    }
#undef LD64
#pragma unroll
    for (int i = 0; i < 2; i++)
#pragma unroll
        for (int j = 0; j < 2; j++) {
            const int col = n0 + wn + j * 16 + lr;      // C/D: col=lane&15
            const int row = m0 + wm + i * 16 + lq * 4;  //      row=quad*4+reg
#pragma unroll
            for (int rr = 0; rr < 4; rr++)
                unsafeAtomicAdd(&C[(size_t)(row + rr) * N + col], acc[i][j][rr]);
        }
}

// 32x64 tile, 4 waves (16x32 each); direct+bias or split-K atomic epilogue.
template <bool ATOMIC>
__device__ __forceinline__ void gemm32(
    const unsigned short* __restrict__ A, const unsigned short* __restrict__ BT,
    const float* __restrict__ bias, float* __restrict__ C,
    int m0, int n0, int K, int N, int kbase, int kiters,
    unsigned short* As, unsigned short* Bs) {
    const int t = threadIdx.x;
    const int lane = t & 63, wid = t >> 6;
    const int wm = (wid & 1) * 16, wn = (wid >> 1) * 32;
    const int lr = lane & 15, lq = lane >> 4;
    const int r = t >> 3, c8 = (t & 7) * 8;

    s16x8 ra, rb0, rb1;
#define LD32(kt)                                                           \
    ra  = *(const s16x8*)(A  + (size_t)(m0 + r)      * K + (kt) + c8);     \
    rb0 = *(const s16x8*)(BT + (size_t)(n0 + r)      * K + (kt) + c8);     \
    rb1 = *(const s16x8*)(BT + (size_t)(n0 + r + 32) * K + (kt) + c8);

    f32x4 acc[2] = {};
    LD32(kbase);
    for (int it = 0; it < kiters; it++) {
        __syncthreads();
        *(s16x8*)&As[r * 72 + c8]        = ra;
        *(s16x8*)&Bs[r * 72 + c8]        = rb0;
        *(s16x8*)&Bs[(r + 32) * 72 + c8] = rb1;
        __syncthreads();
        if (it + 1 < kiters) { LD32(kbase + (it + 1) * 64); }  // prefetch
#pragma unroll
        for (int s = 0; s < 2; s++) {
            s16x8 a0 = *(const s16x8*)&As[(wm + lr) * 72      + s * 32 + lq * 8];
            s16x8 b0 = *(const s16x8*)&Bs[(wn + lr) * 72      + s * 32 + lq * 8];
            s16x8 b1 = *(const s16x8*)&Bs[(wn + 16 + lr) * 72 + s * 32 + lq * 8];
            acc[0] = __builtin_amdgcn_mfma_f32_16x16x32_bf16(a0, b0, acc[0], 0, 0, 0);
            acc[1] = __builtin_amdgcn_mfma_f32_16x16x32_bf16(a0, b1, acc[1], 0, 0, 0);
        }
    }
#undef LD32
#pragma unroll
    for (int j = 0; j < 2; j++) {
        const int col = n0 + wn + j * 16 + lr;
        const int row = m0 + wm + lq * 4;
        if (ATOMIC) {
#pragma unroll
            for (int rr = 0; rr < 4; rr++)
                unsafeAtomicAdd(&C[(size_t)(row + rr) * N + col], acc[j][rr]);
        } else {
            const float bv = bias[col];
#pragma unroll
            for (int rr = 0; rr < 4; rr++)
                C[(size_t)(row + rr) * N + col] = acc[j][rr] + bv;
        }
    }
}

// ---------------- stage B: keys split-K x4 + q GEMM -------------------------
__global__ __launch_bounds__(256) void k_stageB(
    const unsigned short* __restrict__ qbf, const unsigned short* __restrict__ abf,
    const unsigned short* __restrict__ WqT, const unsigned short* __restrict__ WsT,
    const float* __restrict__ bq, float* __restrict__ q, float* __restrict__ keys) {
    __shared__ __align__(16) unsigned short As[64 * 72];
    __shared__ __align__(16) unsigned short Bs[64 * 72];
    const int bid = blockIdx.x;
    if (bid < 800) {
        const int c = bid / 200, rem = bid % 200;
        const int mt = rem >> 3, nt = rem & 7;
        gemm64_atomic(abf, WsT, keys, mt * 64, nt * 64, 2048, 512, c * 512, 8, As, Bs);
    } else {
        const int r = bid - 800;
        const int mt = r >> 3, nt = r & 7;
        gemm32<false>(qbf, WqT, bq, q, mt * 32, nt * 64, 512, 512, 0, 8, As, Bs);
    }
}

// ---------------- out = [query,ctx] @ Wo + bo, split-K x2 (atomic) ----------
__global__ __launch_bounds__(256) void k_out(
    const unsigned short* __restrict__ aout, const unsigned short* __restrict__ WoT,
    float* __restrict__ out) {
    __shared__ __align__(16) unsigned short As[64 * 72];
    __shared__ __align__(16) unsigned short Bs[64 * 72];
    const int bid = blockIdx.x;
    const int c = bid >> 8, rem = bid & 255;
    const int mt = rem >> 3, nt = rem & 7;
    gemm32<true>(aout, WoT, nullptr, out, mt * 32, nt * 64, 1024, 512,
                 c * 512, 8, As, Bs);
}

// ---------------- scores + factorized softmax (fp32) ------------------------
__global__ __launch_bounds__(256) void k_scores(
    const float* __restrict__ q, const float* __restrict__ keys,
    float* __restrict__ wsT, float* __restrict__ wtT) {
    __shared__ __align__(16) float qsh[512];
    __shared__ float sc[200];

    const int t = threadIdx.x;
    const int row = blockIdx.x;          // b*128 + l
    const int b = row >> 7, l = row & 127;

    if (t < 128)
        *(float4*)&qsh[t * 4] = *(const float4*)(q + (size_t)row * 512 + t * 4);
    __syncthreads();

    const int wave = t >> 6, lane = t & 63;
    const float4* qp = (const float4*)qsh;
    const float4 qv1 = qp[lane], qv2 = qp[lane + 64];

    for (int idx = wave; idx < 200; idx += 4) {
        const int kr = (idx < 100) ? (b * 100 + idx)
                                   : (800 + b * 100 + (idx - 100));
        const float4* kp = (const float4*)(keys + (size_t)kr * 512);
        const float4 kv1 = kp[lane], kv2 = kp[lane + 64];
        float d = kv1.x * qv1.x + kv1.y * qv1.y + kv1.z * qv1.z + kv1.w * qv1.w
                + kv2.x * qv2.x + kv2.y * qv2.y + kv2.z * qv2.z + kv2.w * qv2.w;
#pragma unroll
        for (int off = 32; off > 0; off >>= 1) d += __shfl_down(d, off);
        if (lane == 0)
            sc[idx] = ((idx < 100) ? d : -d) * (1.0f / 32.0f);  // 1/sqrt(2*512)
    }
    __syncthreads();

    if (wave < 2) {
        const float* sp = sc + wave * 100;
        const bool hi = (lane + 64) < 100;
        const float v0 = sp[lane];
        const float v1 = hi ? sp[lane + 64] : -INFINITY;
        float mx = fmaxf(v0, v1);
#pragma unroll
        for (int off = 32; off > 0; off >>= 1) mx = fmaxf(mx, __shfl_xor(mx, off));
        const float e0 = __expf(v0 - mx);
        const float e1 = hi ? __expf(v1 - mx) : 0.f;
        float s = e0 + e1;
#pragma unroll
        for (int off = 32; off > 0; off >>= 1) s += __shfl_xor(s, off);
        const float inv = 1.f / s;
        float* op = (wave == 0) ? wsT : wtT;
        op[(b * 100 + lane) * 128 + l] = e0 * inv;
        if (hi) op[(b * 100 + lane + 64) * 128 + l] = e1 * inv;
    }
}

// ---------------- ctx -> bf16 into aout cols 512..1023 ----------------------
// grid (16 n-tiles, 8 b, 4 l-tiles) = 512 blocks; 32(l) x 32(n), K=200,
// 5 chunks of 40 with register prefetch.
__global__ __launch_bounds__(256) void k_ctx(
    const float* __restrict__ wsT, const float* __restrict__ wtT,
    const float* __restrict__ keys, unsigned short* __restrict__ aout) {
    __shared__ float As[40][32];   // As[k][l]
    __shared__ float Bs[40][32];   // Bs[k][n]

    const int t = threadIdx.x;
    const int b = blockIdx.y;
    const int n0 = blockIdx.x * 32;
    const int l0 = blockIdx.z * 32;
    const int tx = t & 7, ty = t >> 3;   // tx: n/4, ty: l

    float rA[5], rB[5];
    auto loadc = [&](int kbase) {
#pragma unroll
        for (int e = 0; e < 5; e++) {
            const int idx = t + e * 256;
            const int k = idx >> 5, j = idx & 31;
            const int kk = kbase + k;
            rA[e] = (kk < 100) ? wsT[(b * 100 + kk) * 128 + l0 + j]
                               : wtT[(b * 100 + (kk - 100)) * 128 + l0 + j];
            rB[e] = (kk < 100)
                ?  keys[(size_t)(b * 100 + kk) * 512 + n0 + j]
                : -keys[(size_t)(800 + b * 100 + (kk - 100)) * 512 + n0 + j];
        }
    };

    float acc[4] = {};
    loadc(0);
    for (int c5 = 0; c5 < 5; c5++) {
        __syncthreads();
#pragma unroll
        for (int e = 0; e < 5; e++) {
            const int idx = t + e * 256;
            As[idx >> 5][idx & 31] = rA[e];
            Bs[idx >> 5][idx & 31] = rB[e];
        }
        __syncthreads();
        if (c5 < 4) loadc((c5 + 1) * 40);          // prefetch next chunk
#pragma unroll 8
        for (int k = 0; k < 40; k++) {
            const float ar = As[k][ty];
            float br[4];
            *(float4*)br = *(const float4*)&Bs[k][tx * 4];
#pragma unroll
            for (int j = 0; j < 4; j++) acc[j] = fmaf(ar, br[j], acc[j]);
        }
    }

    const float s2 = 0.70710678118654752f;  // 1/sqrt(2)
    const int m = b * 128 + l0 + ty;
    ushort4 o = make_ushort4(f2bf(acc[0] * s2), f2bf(acc[1] * s2),
                             f2bf(acc[2] * s2), f2bf(acc[3] * s2));
    *(ushort4*)(aout + (size_t)m * 1024 + 512 + n0 + tx * 4) = o;
}

// ---------------- launch ----------------------------------------------------

extern "C" void kernel_launch(void* const* d_in, const int* in_sizes, int n_in,
                              void* d_out, int out_size, void* d_ws, size_t ws_size,
                              hipStream_t stream) {
    const float* query = (const float*)d_in[0];
    const float* src   = (const float*)d_in[1];
    const float* trg   = (const float*)d_in[2];
    const float* Wq    = (const float*)d_in[3];
    const float* bq    = (const float*)d_in[4];
    const float* Ws    = (const float*)d_in[5];
    const float* bs    = (const float*)d_in[6];
    const float* Wo    = (const float*)d_in[7];
    const float* bo    = (const float*)d_in[8];
    float* out = (float*)d_out;

    float* q    = (float*)d_ws;               // 1024*512
    float* keys = q    + 524288;              // 1600*512
    float* wsT  = keys + 819200;              // 8*100*128
    float* wtT  = wsT  + 102400;
    unsigned short* qbf = (unsigned short*)(wtT + 102400);
    unsigned short* abf = qbf + 524288;       // [src;trg] 1600x2048
    unsigned short* aout= abf + 3276800;      // [query,ctx] 1024x1024
    unsigned short* wqt = aout + 1048576;     // WqT 512x512
    unsigned short* wst = wqt  + 262144;      // WsT 512x2048
    unsigned short* wot = wst  + 1048576;     // WoT 512x1024

    k_prep<<<6816, 256, 0, stream>>>(query, src, trg, Wq, Ws, Wo, bs, bo,
                                     qbf, aout, abf, wqt, wst, wot, keys, out);
    k_stageB<<<1056, 256, 0, stream>>>(qbf, abf, wqt, wst, bq, q, keys);
    k_scores<<<1024, 256, 0, stream>>>(q, keys, wsT, wtT);
    k_ctx<<<dim3(16, 8, 4), 256, 0, stream>>>(wsT, wtT, keys, aout);
    k_out<<<512, 256, 0, stream>>>(aout, wot, out);
}

// Round 7
// 132.736 us; speedup vs baseline: 2.9701x; 1.1332x over previous
//
#include <hip/hip_runtime.h>
#include <math.h>

// DynamicAttention1 — round 7: MFMA scores + softmax fused into ctx.
// R6 accounting: ~56us fixed harness overhead (268MB poison fill) + ~94us
// kernels/gaps. k_scores was L2-BW-bound (420MB keys re-reads). Changes:
//   * k_scgemm: sc = qh @ keys^T per batch (MFMA, splitK x2, in-register
//     fp32->bf16 of keys, scale 1/32 + t-sign in epilogue) -> 26MB L2
//   * softmax moved INTO k_ctx (per-block redundant, trivial cost); wsT/wtT
//     buffers and kernel eliminated; launch count stays 5
//   * q-GEMM writes bf16 qh directly (fp32 q dropped)
// Launches: prep -> stageB(keys splitKx4 + q->qh) -> scgemm -> ctx -> out

typedef __attribute__((ext_vector_type(8))) short s16x8;
typedef __attribute__((ext_vector_type(4))) float f32x4;

__device__ __forceinline__ unsigned short f2bf(float f) {
    unsigned int u = __float_as_uint(f);
    return (unsigned short)((u + 0x7fffu + ((u >> 16) & 1u)) >> 16);  // RNE
}

// ---------------- prep: casts + weight transposes + inits -------------------
__global__ __launch_bounds__(256) void k_prep(
    const float* __restrict__ query, const float* __restrict__ src,
    const float* __restrict__ trg, const float* __restrict__ Wq,
    const float* __restrict__ Ws, const float* __restrict__ Wo,
    const float* __restrict__ bs, const float* __restrict__ bo,
    unsigned short* __restrict__ qbf, unsigned short* __restrict__ aout,
    unsigned short* __restrict__ abf, unsigned short* __restrict__ WqT,
    unsigned short* __restrict__ WsT, unsigned short* __restrict__ WoT,
    float* __restrict__ keys, float* __restrict__ out, float* __restrict__ sc) {
    __shared__ float tile[32][33];
    const int bid = blockIdx.x, t = threadIdx.x;

    if (bid < 3712) {                       // activation casts (float4 groups)
        const int idx = bid * 256 + t;
        if (idx < 131072) {
            float4 v = *(const float4*)(query + (size_t)idx * 4);
            ushort4 o = make_ushort4(f2bf(v.x), f2bf(v.y), f2bf(v.z), f2bf(v.w));
            *(ushort4*)(qbf + (size_t)idx * 4) = o;
            const int flat = idx * 4, m = flat >> 9, c = flat & 511;
            *(ushort4*)(aout + (size_t)m * 1024 + c) = o;   // A_out left half
        } else if (idx < 540672) {
            const int i = idx - 131072;
            float4 v = *(const float4*)(src + (size_t)i * 4);
            *(ushort4*)(abf + (size_t)i * 4) =
                make_ushort4(f2bf(v.x), f2bf(v.y), f2bf(v.z), f2bf(v.w));
        } else {
            const int i = idx - 540672;
            float4 v = *(const float4*)(trg + (size_t)i * 4);
            *(ushort4*)(abf + 1638400 + (size_t)i * 4) =
                make_ushort4(f2bf(v.x), f2bf(v.y), f2bf(v.z), f2bf(v.w));
        }
    } else if (bid < 5504) {                // weight transpose-cast, 32x32 tiles
        const int id = bid - 3712;
        const float* W; unsigned short* O; int K, tk, tn;
        if (id < 256)       { W = Wq; O = WqT; K = 512;  tk = id >> 4;          tn = id & 15; }
        else if (id < 1280) { W = Ws; O = WsT; K = 2048; tk = (id - 256) >> 4;  tn = (id - 256) & 15; }
        else                { W = Wo; O = WoT; K = 1024; tk = (id - 1280) >> 4; tn = (id - 1280) & 15; }
        const int row = t >> 3, c4 = (t & 7) * 4;
        float4 v = *(const float4*)(W + (size_t)(tk * 32 + row) * 512 + tn * 32 + c4);
        tile[row][c4 + 0] = v.x; tile[row][c4 + 1] = v.y;
        tile[row][c4 + 2] = v.z; tile[row][c4 + 3] = v.w;
        __syncthreads();
        ushort4 o = make_ushort4(f2bf(tile[c4 + 0][row]), f2bf(tile[c4 + 1][row]),
                                 f2bf(tile[c4 + 2][row]), f2bf(tile[c4 + 3][row]));
        *(ushort4*)(O + (size_t)(tn * 32 + row) * K + tk * 32 + c4) = o;
    } else if (bid < 6304) {                // keys = broadcast bs (split-K base)
        const int f = ((bid - 5504) * 256 + t) * 4;
        *(float4*)(keys + f) = *(const float4*)(bs + (f & 511));
    } else if (bid < 6816) {                // out = broadcast bo (split-K base)
        const int f = ((bid - 6304) * 256 + t) * 4;
        *(float4*)(out + f) = *(const float4*)(bo + (f & 511));
    } else {                                // sc = 0 (split-K base)
        const int f = ((bid - 6816) * 256 + t) * 4;
        *(float4*)(sc + f) = make_float4(0.f, 0.f, 0.f, 0.f);
    }
}

// ---------------- MFMA GEMM bodies (register-prefetch pipelined) ------------
// A [M][K] bf16, BT [N][K] bf16. LDS rows padded to 72 bf16 (144 B).

// 64x64 tile, 4 waves 2x2; split-K partial accumulated via fp32 atomics.
__device__ __forceinline__ void gemm64_atomic(
    const unsigned short* __restrict__ A, const unsigned short* __restrict__ BT,
    float* __restrict__ C, int m0, int n0, int K, int N, int kbase, int kiters,
    unsigned short* As, unsigned short* Bs) {
    const int t = threadIdx.x;
    const int lane = t & 63, wid = t >> 6;
    const int wm = (wid & 1) * 32, wn = (wid >> 1) * 32;
    const int lr = lane & 15, lq = lane >> 4;
    const int r = t >> 3, c8 = (t & 7) * 8;       // staging coords

    s16x8 ra0, ra1, rb0, rb1;
#define LD64(kt)                                                           \
    ra0 = *(const s16x8*)(A  + (size_t)(m0 + r)      * K + (kt) + c8);     \
    ra1 = *(const s16x8*)(A  + (size_t)(m0 + r + 32) * K + (kt) + c8);     \
    rb0 = *(const s16x8*)(BT + (size_t)(n0 + r)      * K + (kt) + c8);     \
    rb1 = *(const s16x8*)(BT + (size_t)(n0 + r + 32) * K + (kt) + c8);

    f32x4 acc[2][2] = {};
    LD64(kbase);
    for (int it = 0; it < kiters; it++) {
        __syncthreads();                   // previous tile fully consumed
        *(s16x8*)&As[r * 72 + c8]        = ra0;
        *(s16x8*)&As[(r + 32) * 72 + c8] = ra1;
        *(s16x8*)&Bs[r * 72 + c8]        = rb0;
        *(s16x8*)&Bs[(r + 32) * 72 + c8] = rb1;
        __syncthreads();
        if (it + 1 < kiters) { LD64(kbase + (it + 1) * 64); }  // prefetch
#pragma unroll
        for (int s = 0; s < 2; s++) {
            s16x8 a0 = *(const s16x8*)&As[(wm + lr) * 72      + s * 32 + lq * 8];
            s16x8 a1 = *(const s16x8*)&As[(wm + 16 + lr) * 72 + s * 32 + lq * 8];
            s16x8 b0 = *(const s16x8*)&Bs[(wn + lr) * 72      + s * 32 + lq * 8];
            s16x8 b1 = *(const s16x8*)&Bs[(wn + 16 + lr) * 72 + s * 32 + lq * 8];
            acc[0][0] = __builtin_amdgcn_mfma_f32_16x16x32_bf16(a0, b0, acc[0][0], 0, 0, 0);
            acc[0][1] = __builtin_amdgcn_mfma_f32_16x16x32_bf16(a0, b1, acc[0][1], 0, 0, 0);
            acc[1][0] = __builtin_amdgcn_mfma_f32_16x16x32_bf16(a1, b0, acc[1][0], 0, 0, 0);
            acc[1][1] = __builtin_amdgcn_mfma_f32_16x16x32_bf16(a1, b1, acc[1][1], 0, 0, 0);
        }
    }
#undef LD64
#pragma unroll
    for (int i = 0; i < 2; i++)
#pragma unroll
        for (int j = 0; j < 2; j++) {
            const int col = n0 + wn + j * 16 + lr;      // C/D: col=lane&15
            const int row = m0 + wm + i * 16 + lq * 4;  //      row=quad*4+reg
#pragma unroll
            for (int rr = 0; rr < 4; rr++)
                unsafeAtomicAdd(&C[(size_t)(row + rr) * N + col], acc[i][j][rr]);
        }
}

// 32x64 tile, 4 waves (16x32 each). MODE 0: fp32+bias, 1: atomic, 2: bf16+bias
template <int MODE>
__device__ __forceinline__ void gemm32(
    const unsigned short* __restrict__ A, const unsigned short* __restrict__ BT,
    const float* __restrict__ bias, void* __restrict__ Cv,
    int m0, int n0, int K, int N, int kbase, int kiters,
    unsigned short* As, unsigned short* Bs) {
    const int t = threadIdx.x;
    const int lane = t & 63, wid = t >> 6;
    const int wm = (wid & 1) * 16, wn = (wid >> 1) * 32;
    const int lr = lane & 15, lq = lane >> 4;
    const int r = t >> 3, c8 = (t & 7) * 8;

    s16x8 ra, rb0, rb1;
#define LD32(kt)                                                           \
    ra  = *(const s16x8*)(A  + (size_t)(m0 + r)      * K + (kt) + c8);     \
    rb0 = *(const s16x8*)(BT + (size_t)(n0 + r)      * K + (kt) + c8);     \
    rb1 = *(const s16x8*)(BT + (size_t)(n0 + r + 32) * K + (kt) + c8);

    f32x4 acc[2] = {};
    LD32(kbase);
    for (int it = 0; it < kiters; it++) {
        __syncthreads();
        *(s16x8*)&As[r * 72 + c8]        = ra;
        *(s16x8*)&Bs[r * 72 + c8]        = rb0;
        *(s16x8*)&Bs[(r + 32) * 72 + c8] = rb1;
        __syncthreads();
        if (it + 1 < kiters) { LD32(kbase + (it + 1) * 64); }  // prefetch
#pragma unroll
        for (int s = 0; s < 2; s++) {
            s16x8 a0 = *(const s16x8*)&As[(wm + lr) * 72      + s * 32 + lq * 8];
            s16x8 b0 = *(const s16x8*)&Bs[(wn + lr) * 72      + s * 32 + lq * 8];
            s16x8 b1 = *(const s16x8*)&Bs[(wn + 16 + lr) * 72 + s * 32 + lq * 8];
            acc[0] = __builtin_amdgcn_mfma_f32_16x16x32_bf16(a0, b0, acc[0], 0, 0, 0);
            acc[1] = __builtin_amdgcn_mfma_f32_16x16x32_bf16(a0, b1, acc[1], 0, 0, 0);
        }
    }
#undef LD32
#pragma unroll
    for (int j = 0; j < 2; j++) {
        const int col = n0 + wn + j * 16 + lr;
        const int row = m0 + wm + lq * 4;
        if (MODE == 1) {
            float* C = (float*)Cv;
#pragma unroll
            for (int rr = 0; rr < 4; rr++)
                unsafeAtomicAdd(&C[(size_t)(row + rr) * N + col], acc[j][rr]);
        } else if (MODE == 0) {
            float* C = (float*)Cv;
            const float bv = bias[col];
#pragma unroll
            for (int rr = 0; rr < 4; rr++)
                C[(size_t)(row + rr) * N + col] = acc[j][rr] + bv;
        } else {
            unsigned short* C = (unsigned short*)Cv;
            const float bv = bias[col];
#pragma unroll
            for (int rr = 0; rr < 4; rr++)
                C[(size_t)(row + rr) * N + col] = f2bf(acc[j][rr] + bv);
        }
    }
}

// ---------------- stage B: keys split-K x4 + q GEMM (-> bf16 qh) ------------
__global__ __launch_bounds__(256) void k_stageB(
    const unsigned short* __restrict__ qbf, const unsigned short* __restrict__ abf,
    const unsigned short* __restrict__ WqT, const unsigned short* __restrict__ WsT,
    const float* __restrict__ bq, unsigned short* __restrict__ qh,
    float* __restrict__ keys) {
    __shared__ __align__(16) unsigned short As[64 * 72];
    __shared__ __align__(16) unsigned short Bs[64 * 72];
    const int bid = blockIdx.x;
    if (bid < 800) {
        const int c = bid / 200, rem = bid % 200;
        const int mt = rem >> 3, nt = rem & 7;
        gemm64_atomic(abf, WsT, keys, mt * 64, nt * 64, 2048, 512, c * 512, 8, As, Bs);
    } else {
        const int r = bid - 800;
        const int mt = r >> 3, nt = r & 7;
        gemm32<2>(qbf, WqT, bq, qh, mt * 32, nt * 64, 512, 512, 0, 8, As, Bs);
    }
}

// ---------------- sc = qh @ keys^T per batch (MFMA, split-K x2) -------------
// sc[b*128+l][n], n in [0,256): cols 0..99 = qs/32, cols 128..227 = -qt/32.
// keys staged with in-register fp32->bf16. 256 blocks.
__global__ __launch_bounds__(256) void k_scgemm(
    const unsigned short* __restrict__ qh, const float* __restrict__ keys,
    float* __restrict__ sc) {
    __shared__ __align__(16) unsigned short As[32 * 72];
    __shared__ __align__(16) unsigned short Bs[64 * 72];
    const int bid = blockIdx.x;
    const int c = bid >> 7, rem = bid & 127;
    const int mt = rem >> 2, nt = rem & 3;
    const int m0 = mt * 32, b = mt >> 2, n0 = nt * 64;
    const int kbase = c * 256;
    const int t = threadIdx.x;
    const int lane = t & 63, wid = t >> 6;
    const int wm = (wid & 1) * 16, wn = (wid >> 1) * 32;
    const int lr = lane & 15, lq = lane >> 4;
    const int r = t >> 3, c8 = (t & 7) * 8;

    // BT row mapping (constant across K); clamp keeps reads in-bounds,
    // garbage lands only in invalid cols (100..127, 228..255).
    const int nA = n0 + r, nB = n0 + r + 32;
    int kr0 = (nA < 128) ? (b * 100 + nA) : (800 + b * 100 + (nA - 128));
    int kr1 = (nB < 128) ? (b * 100 + nB) : (800 + b * 100 + (nB - 128));
    kr0 = kr0 > 1599 ? 1599 : kr0;
    kr1 = kr1 > 1599 ? 1599 : kr1;

    s16x8 ra, rb0, rb1;
    auto cvt8 = [](const float* p) {
        float4 u = *(const float4*)p, w = *(const float4*)(p + 4);
        s16x8 o;
        o[0] = (short)f2bf(u.x); o[1] = (short)f2bf(u.y);
        o[2] = (short)f2bf(u.z); o[3] = (short)f2bf(u.w);
        o[4] = (short)f2bf(w.x); o[5] = (short)f2bf(w.y);
        o[6] = (short)f2bf(w.z); o[7] = (short)f2bf(w.w);
        return o;
    };
#define LDSC(kt)                                                   \
    ra  = *(const s16x8*)(qh + (size_t)(m0 + r) * 512 + (kt) + c8); \
    rb0 = cvt8(keys + (size_t)kr0 * 512 + (kt) + c8);               \
    rb1 = cvt8(keys + (size_t)kr1 * 512 + (kt) + c8);

    f32x4 acc[2] = {};
    LDSC(kbase);
    for (int it = 0; it < 4; it++) {
        __syncthreads();
        *(s16x8*)&As[r * 72 + c8]        = ra;
        *(s16x8*)&Bs[r * 72 + c8]        = rb0;
        *(s16x8*)&Bs[(r + 32) * 72 + c8] = rb1;
        __syncthreads();
        if (it < 3) { LDSC(kbase + (it + 1) * 64); }
#pragma unroll
        for (int s = 0; s < 2; s++) {
            s16x8 a0 = *(const s16x8*)&As[(wm + lr) * 72      + s * 32 + lq * 8];
            s16x8 b0 = *(const s16x8*)&Bs[(wn + lr) * 72      + s * 32 + lq * 8];
            s16x8 b1 = *(const s16x8*)&Bs[(wn + 16 + lr) * 72 + s * 32 + lq * 8];
            acc[0] = __builtin_amdgcn_mfma_f32_16x16x32_bf16(a0, b0, acc[0], 0, 0, 0);
            acc[1] = __builtin_amdgcn_mfma_f32_16x16x32_bf16(a0, b1, acc[1], 0, 0, 0);
        }
    }
#undef LDSC
#pragma unroll
    for (int j = 0; j < 2; j++) {
        const int col = n0 + wn + j * 16 + lr;
        const int row = m0 + wm + lq * 4;
        const float scale = (col >= 128) ? -(1.0f / 32.0f) : (1.0f / 32.0f);
#pragma unroll
        for (int rr = 0; rr < 4; rr++)
            unsafeAtomicAdd(&sc[(size_t)(row + rr) * 256 + col],
                            acc[j][rr] * scale);
    }
}

// ---------------- ctx: in-block softmax + GEMM -> bf16 aout -----------------
// grid (16 n-tiles, 8 b, 4 l-tiles) = 512 blocks of 32(l) x 32(n), K=200.
// Each block redoes the masked softmax for its 32 l-rows from sc (cheap),
// builds w[st][l] in LDS, then GEMMs against [skey;-tkey].
__global__ __launch_bounds__(256) void k_ctx(
    const float* __restrict__ sc, const float* __restrict__ keys,
    unsigned short* __restrict__ aout) {
    __shared__ float wbuf[200 * 33];     // [st][l], pad 33 breaks bank aliasing
    __shared__ float Bs[40 * 32];        // [k][n]

    const int t = threadIdx.x;
    const int b = blockIdx.y;
    const int n0 = blockIdx.x * 32;
    const int l0 = blockIdx.z * 32;
    const int wave = t >> 6, lane = t & 63;

    // ---- softmax: each wave handles 8 rows; lane covers cols lane*4..+3 ----
    for (int i = 0; i < 8; i++) {
        const int li = wave * 8 + i;                  // 0..31
        const float4 v = *(const float4*)(
            sc + (size_t)(b * 128 + l0 + li) * 256 + lane * 4);
        const float vv[4] = {v.x, v.y, v.z, v.w};
        const int c0 = lane * 4;
        float mS = -1e30f, mT = -1e30f;
#pragma unroll
        for (int j = 0; j < 4; j++) {
            const int col = c0 + j;
            if (col < 100) mS = fmaxf(mS, vv[j]);
            if (col >= 128 && col < 228) mT = fmaxf(mT, vv[j]);
        }
#pragma unroll
        for (int off = 32; off > 0; off >>= 1) {
            mS = fmaxf(mS, __shfl_xor(mS, off));
            mT = fmaxf(mT, __shfl_xor(mT, off));
        }
        float eS[4], eT[4], sS = 0.f, sT = 0.f;
#pragma unroll
        for (int j = 0; j < 4; j++) {
            const int col = c0 + j;
            eS[j] = (col < 100) ? __expf(vv[j] - mS) : 0.f;
            eT[j] = (col >= 128 && col < 228) ? __expf(vv[j] - mT) : 0.f;
            sS += eS[j]; sT += eT[j];
        }
#pragma unroll
        for (int off = 32; off > 0; off >>= 1) {
            sS += __shfl_xor(sS, off);
            sT += __shfl_xor(sT, off);
        }
        const float iS = 1.f / sS, iT = 1.f / sT;
#pragma unroll
        for (int j = 0; j < 4; j++) {
            const int col = c0 + j;
            if (col < 100) wbuf[col * 33 + li] = eS[j] * iS;
            if (col >= 128 && col < 228)
                wbuf[(100 + col - 128) * 33 + li] = eT[j] * iT;
        }
    }
    __syncthreads();

    // ---- GEMM: acc[l][n] += w[st][l] * (+skey|-tkey)[st][n] ----------------
    const int tx = t & 7, ty = t >> 3;   // tx: n/4, ty: l
    float rB[5];
    auto loadB = [&](int kbase) {
#pragma unroll
        for (int e = 0; e < 5; e++) {
            const int idx = t + e * 256;
            const int k = idx >> 5, j = idx & 31;
            const int kk = kbase + k;
            rB[e] = (kk < 100)
                ?  keys[(size_t)(b * 100 + kk) * 512 + n0 + j]
                : -keys[(size_t)(800 + b * 100 + (kk - 100)) * 512 + n0 + j];
        }
    };

    float acc[4] = {};
    loadB(0);
    for (int c5 = 0; c5 < 5; c5++) {
        __syncthreads();
#pragma unroll
        for (int e = 0; e < 5; e++) {
            const int idx = t + e * 256;
            Bs[idx] = rB[e];
        }
        __syncthreads();
        if (c5 < 4) loadB((c5 + 1) * 40);          // prefetch next chunk
#pragma unroll 8
        for (int k = 0; k < 40; k++) {
            const float ar = wbuf[(c5 * 40 + k) * 33 + ty];
            float br[4];
            *(float4*)br = *(const float4*)&Bs[k * 32 + tx * 4];
#pragma unroll
            for (int j = 0; j < 4; j++) acc[j] = fmaf(ar, br[j], acc[j]);
        }
    }

    const float s2 = 0.70710678118654752f;  // 1/sqrt(2)
    const int m = b * 128 + l0 + ty;
    ushort4 o = make_ushort4(f2bf(acc[0] * s2), f2bf(acc[1] * s2),
                             f2bf(acc[2] * s2), f2bf(acc[3] * s2));
    *(ushort4*)(aout + (size_t)m * 1024 + 512 + n0 + tx * 4) = o;
}

// ---------------- out = [query,ctx] @ Wo + bo, split-K x2 (atomic) ----------
__global__ __launch_bounds__(256) void k_out(
    const unsigned short* __restrict__ aout, const unsigned short* __restrict__ WoT,
    float* __restrict__ out) {
    __shared__ __align__(16) unsigned short As[64 * 72];
    __shared__ __align__(16) unsigned short Bs[64 * 72];
    const int bid = blockIdx.x;
    const int c = bid >> 8, rem = bid & 255;
    const int mt = rem >> 3, nt = rem & 7;
    gemm32<1>(aout, WoT, nullptr, out, mt * 32, nt * 64, 1024, 512,
              c * 512, 8, As, Bs);
}

// ---------------- launch ----------------------------------------------------

extern "C" void kernel_launch(void* const* d_in, const int* in_sizes, int n_in,
                              void* d_out, int out_size, void* d_ws, size_t ws_size,
                              hipStream_t stream) {
    const float* query = (const float*)d_in[0];
    const float* src   = (const float*)d_in[1];
    const float* trg   = (const float*)d_in[2];
    const float* Wq    = (const float*)d_in[3];
    const float* bq    = (const float*)d_in[4];
    const float* Ws    = (const float*)d_in[5];
    const float* bs    = (const float*)d_in[6];
    const float* Wo    = (const float*)d_in[7];
    const float* bo    = (const float*)d_in[8];
    float* out = (float*)d_out;

    float* keys = (float*)d_ws;               // 1600*512
    float* sc   = keys + 819200;              // 1024*256
    unsigned short* qbf = (unsigned short*)(sc + 262144);  // query bf16 1024x512
    unsigned short* qh  = qbf + 524288;       // hidden q bf16 1024x512
    unsigned short* abf = qh  + 524288;       // [src;trg] 1600x2048
    unsigned short* aout= abf + 3276800;      // [query,ctx] 1024x1024
    unsigned short* wqt = aout + 1048576;     // WqT 512x512
    unsigned short* wst = wqt  + 262144;      // WsT 512x2048
    unsigned short* wot = wst  + 1048576;     // WoT 512x1024

    k_prep<<<7072, 256, 0, stream>>>(query, src, trg, Wq, Ws, Wo, bs, bo,
                                     qbf, aout, abf, wqt, wst, wot,
                                     keys, out, sc);
    k_stageB<<<1056, 256, 0, stream>>>(qbf, abf, wqt, wst, bq, qh, keys);
    k_scgemm<<<256, 256, 0, stream>>>(qh, keys, sc);
    k_ctx<<<dim3(16, 8, 4), 256, 0, stream>>>(sc, keys, aout);
    k_out<<<512, 256, 0, stream>>>(aout, wot, out);
}

// Round 8
// 132.559 us; speedup vs baseline: 2.9740x; 1.0013x over previous
//
#include <hip/hip_runtime.h>
#include <math.h>

// DynamicAttention1 — round 8: atomic diet.
// R7 accounting left ~40us unexplained vs bottom-up kernel ideals; prime
// suspect is 5.8M scalar fp32 atomicAdds in the split-K epilogues (L2 atomic
// units ~1 op/ch/cyc). Changes:
//   * keys split-K x4 -> x2            (3.2M -> 1.6M atomics, 16-iter chains)
//   * out = query@WoTop (direct, in stageB) + ctx@WoBot (k_out, 0.5M atomics)
//     -> out-bias init pass dropped (bias added in the direct part)
//   * scgemm: no split-K, direct store  (0 atomics, sc zero-init dropped)
//   * qbf buffer dropped (q-GEMM reads query bf16 from aout left half)
// Launches: prep -> stageB(keys x2 + q + out_left) -> scgemm -> ctx -> out_right

typedef __attribute__((ext_vector_type(8))) short s16x8;
typedef __attribute__((ext_vector_type(4))) float f32x4;

__device__ __forceinline__ unsigned short f2bf(float f) {
    unsigned int u = __float_as_uint(f);
    return (unsigned short)((u + 0x7fffu + ((u >> 16) & 1u)) >> 16);  // RNE
}

// ---------------- prep: casts + weight transposes + keys bias init ----------
__global__ __launch_bounds__(256) void k_prep(
    const float* __restrict__ query, const float* __restrict__ src,
    const float* __restrict__ trg, const float* __restrict__ Wq,
    const float* __restrict__ Ws, const float* __restrict__ Wo,
    const float* __restrict__ bs,
    unsigned short* __restrict__ aout, unsigned short* __restrict__ abf,
    unsigned short* __restrict__ WqT, unsigned short* __restrict__ WsT,
    unsigned short* __restrict__ WoT, float* __restrict__ keys) {
    __shared__ float tile[32][33];
    const int bid = blockIdx.x, t = threadIdx.x;

    if (bid < 3712) {                       // activation casts (float4 groups)
        const int idx = bid * 256 + t;
        if (idx < 131072) {
            float4 v = *(const float4*)(query + (size_t)idx * 4);
            ushort4 o = make_ushort4(f2bf(v.x), f2bf(v.y), f2bf(v.z), f2bf(v.w));
            const int flat = idx * 4, m = flat >> 9, c = flat & 511;
            *(ushort4*)(aout + (size_t)m * 1024 + c) = o;   // A_out left half
        } else if (idx < 540672) {
            const int i = idx - 131072;
            float4 v = *(const float4*)(src + (size_t)i * 4);
            *(ushort4*)(abf + (size_t)i * 4) =
                make_ushort4(f2bf(v.x), f2bf(v.y), f2bf(v.z), f2bf(v.w));
        } else {
            const int i = idx - 540672;
            float4 v = *(const float4*)(trg + (size_t)i * 4);
            *(ushort4*)(abf + 1638400 + (size_t)i * 4) =
                make_ushort4(f2bf(v.x), f2bf(v.y), f2bf(v.z), f2bf(v.w));
        }
    } else if (bid < 5504) {                // weight transpose-cast, 32x32 tiles
        const int id = bid - 3712;
        const float* W; unsigned short* O; int K, tk, tn;
        if (id < 256)       { W = Wq; O = WqT; K = 512;  tk = id >> 4;          tn = id & 15; }
        else if (id < 1280) { W = Ws; O = WsT; K = 2048; tk = (id - 256) >> 4;  tn = (id - 256) & 15; }
        else                { W = Wo; O = WoT; K = 1024; tk = (id - 1280) >> 4; tn = (id - 1280) & 15; }
        const int row = t >> 3, c4 = (t & 7) * 4;
        float4 v = *(const float4*)(W + (size_t)(tk * 32 + row) * 512 + tn * 32 + c4);
        tile[row][c4 + 0] = v.x; tile[row][c4 + 1] = v.y;
        tile[row][c4 + 2] = v.z; tile[row][c4 + 3] = v.w;
        __syncthreads();
        ushort4 o = make_ushort4(f2bf(tile[c4 + 0][row]), f2bf(tile[c4 + 1][row]),
                                 f2bf(tile[c4 + 2][row]), f2bf(tile[c4 + 3][row]));
        *(ushort4*)(O + (size_t)(tn * 32 + row) * K + tk * 32 + c4) = o;
    } else {                                // keys = broadcast bs (split-K base)
        const int f = ((bid - 5504) * 256 + t) * 4;
        *(float4*)(keys + f) = *(const float4*)(bs + (f & 511));
    }
}

// ---------------- MFMA GEMM bodies (register-prefetch pipelined) ------------
// A [M][KA] bf16 (k window kbase..), BT [N][KB] bf16. LDS rows pad 72 (144 B).

// 64x64 tile, 4 waves 2x2; split-K partial accumulated via fp32 atomics.
__device__ __forceinline__ void gemm64_atomic(
    const unsigned short* __restrict__ A, const unsigned short* __restrict__ BT,
    float* __restrict__ C, int m0, int n0, int K, int N, int kbase, int kiters,
    unsigned short* As, unsigned short* Bs) {
    const int t = threadIdx.x;
    const int lane = t & 63, wid = t >> 6;
    const int wm = (wid & 1) * 32, wn = (wid >> 1) * 32;
    const int lr = lane & 15, lq = lane >> 4;
    const int r = t >> 3, c8 = (t & 7) * 8;       // staging coords

    s16x8 ra0, ra1, rb0, rb1;
#define LD64(kt)                                                           \
    ra0 = *(const s16x8*)(A  + (size_t)(m0 + r)      * K + (kt) + c8);     \
    ra1 = *(const s16x8*)(A  + (size_t)(m0 + r + 32) * K + (kt) + c8);     \
    rb0 = *(const s16x8*)(BT + (size_t)(n0 + r)      * K + (kt) + c8);     \
    rb1 = *(const s16x8*)(BT + (size_t)(n0 + r + 32) * K + (kt) + c8);

    f32x4 acc[2][2] = {};
    LD64(kbase);
    for (int it = 0; it < kiters; it++) {
        __syncthreads();                   // previous tile fully consumed
        *(s16x8*)&As[r * 72 + c8]        = ra0;
        *(s16x8*)&As[(r + 32) * 72 + c8] = ra1;
        *(s16x8*)&Bs[r * 72 + c8]        = rb0;
        *(s16x8*)&Bs[(r + 32) * 72 + c8] = rb1;
        __syncthreads();
        if (it + 1 < kiters) { LD64(kbase + (it + 1) * 64); }  // prefetch
#pragma unroll
        for (int s = 0; s < 2; s++) {
            s16x8 a0 = *(const s16x8*)&As[(wm + lr) * 72      + s * 32 + lq * 8];
            s16x8 a1 = *(const s16x8*)&As[(wm + 16 + lr) * 72 + s * 32 + lq * 8];
            s16x8 b0 = *(const s16x8*)&Bs[(wn + lr) * 72      + s * 32 + lq * 8];
            s16x8 b1 = *(const s16x8*)&Bs[(wn + 16 + lr) * 72 + s * 32 + lq * 8];
            acc[0][0] = __builtin_amdgcn_mfma_f32_16x16x32_bf16(a0, b0, acc[0][0], 0, 0, 0);
            acc[0][1] = __builtin_amdgcn_mfma_f32_16x16x32_bf16(a0, b1, acc[0][1], 0, 0, 0);
            acc[1][0] = __builtin_amdgcn_mfma_f32_16x16x32_bf16(a1, b0, acc[1][0], 0, 0, 0);
            acc[1][1] = __builtin_amdgcn_mfma_f32_16x16x32_bf16(a1, b1, acc[1][1], 0, 0, 0);
        }
    }
#undef LD64
#pragma unroll
    for (int i = 0; i < 2; i++)
#pragma unroll
        for (int j = 0; j < 2; j++) {
            const int col = n0 + wn + j * 16 + lr;      // C/D: col=lane&15
            const int row = m0 + wm + i * 16 + lq * 4;  //      row=quad*4+reg
#pragma unroll
            for (int rr = 0; rr < 4; rr++)
                unsafeAtomicAdd(&C[(size_t)(row + rr) * N + col], acc[i][j][rr]);
        }
}

// 32x64 tile, 4 waves (16x32 each). MODE 0: fp32+bias direct, 1: atomic,
// 2: bf16+bias direct. KA/KB: row strides of A and BT (k window shared).
template <int MODE>
__device__ __forceinline__ void gemm32(
    const unsigned short* __restrict__ A, const unsigned short* __restrict__ BT,
    const float* __restrict__ bias, void* __restrict__ Cv,
    int m0, int n0, int KA, int KB, int N, int kbase, int kiters,
    unsigned short* As, unsigned short* Bs) {
    const int t = threadIdx.x;
    const int lane = t & 63, wid = t >> 6;
    const int wm = (wid & 1) * 16, wn = (wid >> 1) * 32;
    const int lr = lane & 15, lq = lane >> 4;
    const int r = t >> 3, c8 = (t & 7) * 8;

    s16x8 ra, rb0, rb1;
#define LD32(kt)                                                            \
    ra  = *(const s16x8*)(A  + (size_t)(m0 + r)      * KA + (kt) + c8);     \
    rb0 = *(const s16x8*)(BT + (size_t)(n0 + r)      * KB + (kt) + c8);     \
    rb1 = *(const s16x8*)(BT + (size_t)(n0 + r + 32) * KB + (kt) + c8);

    f32x4 acc[2] = {};
    LD32(kbase);
    for (int it = 0; it < kiters; it++) {
        __syncthreads();
        *(s16x8*)&As[r * 72 + c8]        = ra;
        *(s16x8*)&Bs[r * 72 + c8]        = rb0;
        *(s16x8*)&Bs[(r + 32) * 72 + c8] = rb1;
        __syncthreads();
        if (it + 1 < kiters) { LD32(kbase + (it + 1) * 64); }  // prefetch
#pragma unroll
        for (int s = 0; s < 2; s++) {
            s16x8 a0 = *(const s16x8*)&As[(wm + lr) * 72      + s * 32 + lq * 8];
            s16x8 b0 = *(const s16x8*)&Bs[(wn + lr) * 72      + s * 32 + lq * 8];
            s16x8 b1 = *(const s16x8*)&Bs[(wn + 16 + lr) * 72 + s * 32 + lq * 8];
            acc[0] = __builtin_amdgcn_mfma_f32_16x16x32_bf16(a0, b0, acc[0], 0, 0, 0);
            acc[1] = __builtin_amdgcn_mfma_f32_16x16x32_bf16(a0, b1, acc[1], 0, 0, 0);
        }
    }
#undef LD32
#pragma unroll
    for (int j = 0; j < 2; j++) {
        const int col = n0 + wn + j * 16 + lr;
        const int row = m0 + wm + lq * 4;
        if (MODE == 1) {
            float* C = (float*)Cv;
#pragma unroll
            for (int rr = 0; rr < 4; rr++)
                unsafeAtomicAdd(&C[(size_t)(row + rr) * N + col], acc[j][rr]);
        } else if (MODE == 0) {
            float* C = (float*)Cv;
            const float bv = bias[col];
#pragma unroll
            for (int rr = 0; rr < 4; rr++)
                C[(size_t)(row + rr) * N + col] = acc[j][rr] + bv;
        } else {
            unsigned short* C = (unsigned short*)Cv;
            const float bv = bias[col];
#pragma unroll
            for (int rr = 0; rr < 4; rr++)
                C[(size_t)(row + rr) * N + col] = f2bf(acc[j][rr] + bv);
        }
    }
}

// ---------------- stage B: keys splitKx2 + q GEMM + out_left ----------------
// [0,400): keys (64x64 tiles, splitK x2, atomics onto bias-inited keys)
// [400,656): q = query @ Wq + bq -> bf16 qh  (A from aout left half)
// [656,912): out_left = query @ WoTop + bo -> fp32 out (direct)
__global__ __launch_bounds__(256) void k_stageB(
    const unsigned short* __restrict__ aoutA, const unsigned short* __restrict__ abf,
    const unsigned short* __restrict__ WqT, const unsigned short* __restrict__ WsT,
    const unsigned short* __restrict__ WoT, const float* __restrict__ bq,
    const float* __restrict__ bo, unsigned short* __restrict__ qh,
    float* __restrict__ keys, float* __restrict__ out) {
    __shared__ __align__(16) unsigned short As[64 * 72];
    __shared__ __align__(16) unsigned short Bs[64 * 72];
    const int bid = blockIdx.x;
    if (bid < 400) {
        const int c = bid / 200, rem = bid % 200;
        const int mt = rem >> 3, nt = rem & 7;
        gemm64_atomic(abf, WsT, keys, mt * 64, nt * 64, 2048, 512,
                      c * 1024, 16, As, Bs);
    } else if (bid < 656) {
        const int r = bid - 400;
        const int mt = r >> 3, nt = r & 7;
        gemm32<2>(aoutA, WqT, bq, qh, mt * 32, nt * 64, 1024, 512, 512,
                  0, 8, As, Bs);
    } else {
        const int r = bid - 656;
        const int mt = r >> 3, nt = r & 7;
        gemm32<0>(aoutA, WoT, bo, out, mt * 32, nt * 64, 1024, 1024, 512,
                  0, 8, As, Bs);
    }
}

// ---------------- sc = qh @ keys^T per batch (MFMA, direct store) -----------
// sc[b*128+l][n], n in [0,256): cols 0..99 = qs/32, cols 128..227 = -qt/32.
// keys staged with in-register fp32->bf16. 128 blocks, K=512 (8 iters).
__global__ __launch_bounds__(256) void k_scgemm(
    const unsigned short* __restrict__ qh, const float* __restrict__ keys,
    float* __restrict__ sc) {
    __shared__ __align__(16) unsigned short As[32 * 72];
    __shared__ __align__(16) unsigned short Bs[64 * 72];
    const int bid = blockIdx.x;
    const int mt = bid >> 2, nt = bid & 3;
    const int m0 = mt * 32, b = mt >> 2, n0 = nt * 64;
    const int t = threadIdx.x;
    const int lane = t & 63, wid = t >> 6;
    const int wm = (wid & 1) * 16, wn = (wid >> 1) * 32;
    const int lr = lane & 15, lq = lane >> 4;
    const int r = t >> 3, c8 = (t & 7) * 8;

    // BT row mapping (constant across K); clamp keeps reads in-bounds,
    // garbage lands only in invalid cols (100..127, 228..255).
    const int nA = n0 + r, nB = n0 + r + 32;
    int kr0 = (nA < 128) ? (b * 100 + nA) : (800 + b * 100 + (nA - 128));
    int kr1 = (nB < 128) ? (b * 100 + nB) : (800 + b * 100 + (nB - 128));
    kr0 = kr0 > 1599 ? 1599 : kr0;
    kr1 = kr1 > 1599 ? 1599 : kr1;

    s16x8 ra, rb0, rb1;
    auto cvt8 = [](const float* p) {
        float4 u = *(const float4*)p, w = *(const float4*)(p + 4);
        s16x8 o;
        o[0] = (short)f2bf(u.x); o[1] = (short)f2bf(u.y);
        o[2] = (short)f2bf(u.z); o[3] = (short)f2bf(u.w);
        o[4] = (short)f2bf(w.x); o[5] = (short)f2bf(w.y);
        o[6] = (short)f2bf(w.z); o[7] = (short)f2bf(w.w);
        return o;
    };
#define LDSC(kt)                                                    \
    ra  = *(const s16x8*)(qh + (size_t)(m0 + r) * 512 + (kt) + c8); \
    rb0 = cvt8(keys + (size_t)kr0 * 512 + (kt) + c8);               \
    rb1 = cvt8(keys + (size_t)kr1 * 512 + (kt) + c8);

    f32x4 acc[2] = {};
    LDSC(0);
    for (int it = 0; it < 8; it++) {
        __syncthreads();
        *(s16x8*)&As[r * 72 + c8]        = ra;
        *(s16x8*)&Bs[r * 72 + c8]        = rb0;
        *(s16x8*)&Bs[(r + 32) * 72 + c8] = rb1;
        __syncthreads();
        if (it < 7) { LDSC((it + 1) * 64); }
#pragma unroll
        for (int s = 0; s < 2; s++) {
            s16x8 a0 = *(const s16x8*)&As[(wm + lr) * 72      + s * 32 + lq * 8];
            s16x8 b0 = *(const s16x8*)&Bs[(wn + lr) * 72      + s * 32 + lq * 8];
            s16x8 b1 = *(const s16x8*)&Bs[(wn + 16 + lr) * 72 + s * 32 + lq * 8];
            acc[0] = __builtin_amdgcn_mfma_f32_16x16x32_bf16(a0, b0, acc[0], 0, 0, 0);
            acc[1] = __builtin_amdgcn_mfma_f32_16x16x32_bf16(a0, b1, acc[1], 0, 0, 0);
        }
    }
#undef LDSC
#pragma unroll
    for (int j = 0; j < 2; j++) {
        const int col = n0 + wn + j * 16 + lr;
        const int row = m0 + wm + lq * 4;
        const float scale = (col >= 128) ? -(1.0f / 32.0f) : (1.0f / 32.0f);
#pragma unroll
        for (int rr = 0; rr < 4; rr++)
            sc[(size_t)(row + rr) * 256 + col] = acc[j][rr] * scale;
    }
}

// ---------------- ctx: in-block softmax + GEMM -> bf16 aout -----------------
// grid (16 n-tiles, 8 b, 4 l-tiles) = 512 blocks of 32(l) x 32(n), K=200.
__global__ __launch_bounds__(256) void k_ctx(
    const float* __restrict__ sc, const float* __restrict__ keys,
    unsigned short* __restrict__ aout) {
    __shared__ float wbuf[200 * 33];     // [st][l], pad 33 breaks bank aliasing
    __shared__ float Bs[40 * 32];        // [k][n]

    const int t = threadIdx.x;
    const int b = blockIdx.y;
    const int n0 = blockIdx.x * 32;
    const int l0 = blockIdx.z * 32;
    const int wave = t >> 6, lane = t & 63;

    // ---- softmax: each wave handles 8 rows; lane covers cols lane*4..+3 ----
    for (int i = 0; i < 8; i++) {
        const int li = wave * 8 + i;                  // 0..31
        const float4 v = *(const float4*)(
            sc + (size_t)(b * 128 + l0 + li) * 256 + lane * 4);
        const float vv[4] = {v.x, v.y, v.z, v.w};
        const int c0 = lane * 4;
        float mS = -1e30f, mT = -1e30f;
#pragma unroll
        for (int j = 0; j < 4; j++) {
            const int col = c0 + j;
            if (col < 100) mS = fmaxf(mS, vv[j]);
            if (col >= 128 && col < 228) mT = fmaxf(mT, vv[j]);
        }
#pragma unroll
        for (int off = 32; off > 0; off >>= 1) {
            mS = fmaxf(mS, __shfl_xor(mS, off));
            mT = fmaxf(mT, __shfl_xor(mT, off));
        }
        float eS[4], eT[4], sS = 0.f, sT = 0.f;
#pragma unroll
        for (int j = 0; j < 4; j++) {
            const int col = c0 + j;
            eS[j] = (col < 100) ? __expf(vv[j] - mS) : 0.f;
            eT[j] = (col >= 128 && col < 228) ? __expf(vv[j] - mT) : 0.f;
            sS += eS[j]; sT += eT[j];
        }
#pragma unroll
        for (int off = 32; off > 0; off >>= 1) {
            sS += __shfl_xor(sS, off);
            sT += __shfl_xor(sT, off);
        }
        const float iS = 1.f / sS, iT = 1.f / sT;
#pragma unroll
        for (int j = 0; j < 4; j++) {
            const int col = c0 + j;
            if (col < 100) wbuf[col * 33 + li] = eS[j] * iS;
            if (col >= 128 && col < 228)
                wbuf[(100 + col - 128) * 33 + li] = eT[j] * iT;
        }
    }
    __syncthreads();

    // ---- GEMM: acc[l][n] += w[st][l] * (+skey|-tkey)[st][n] ----------------
    const int tx = t & 7, ty = t >> 3;   // tx: n/4, ty: l
    float rB[5];
    auto loadB = [&](int kbase) {
#pragma unroll
        for (int e = 0; e < 5; e++) {
            const int idx = t + e * 256;
            const int k = idx >> 5, j = idx & 31;
            const int kk = kbase + k;
            rB[e] = (kk < 100)
                ?  keys[(size_t)(b * 100 + kk) * 512 + n0 + j]
                : -keys[(size_t)(800 + b * 100 + (kk - 100)) * 512 + n0 + j];
        }
    };

    float acc[4] = {};
    loadB(0);
    for (int c5 = 0; c5 < 5; c5++) {
        __syncthreads();
#pragma unroll
        for (int e = 0; e < 5; e++) {
            const int idx = t + e * 256;
            Bs[idx] = rB[e];
        }
        __syncthreads();
        if (c5 < 4) loadB((c5 + 1) * 40);          // prefetch next chunk
#pragma unroll 8
        for (int k = 0; k < 40; k++) {
            const float ar = wbuf[(c5 * 40 + k) * 33 + ty];
            float br[4];
            *(float4*)br = *(const float4*)&Bs[k * 32 + tx * 4];
#pragma unroll
            for (int j = 0; j < 4; j++) acc[j] = fmaf(ar, br[j], acc[j]);
        }
    }

    const float s2 = 0.70710678118654752f;  // 1/sqrt(2)
    const int m = b * 128 + l0 + ty;
    ushort4 o = make_ushort4(f2bf(acc[0] * s2), f2bf(acc[1] * s2),
                             f2bf(acc[2] * s2), f2bf(acc[3] * s2));
    *(ushort4*)(aout + (size_t)m * 1024 + 512 + n0 + tx * 4) = o;
}

// ---------------- out += ctx @ WoBot (atomic onto out_left result) ----------
__global__ __launch_bounds__(256) void k_out(
    const unsigned short* __restrict__ aout, const unsigned short* __restrict__ WoT,
    float* __restrict__ out) {
    __shared__ __align__(16) unsigned short As[64 * 72];
    __shared__ __align__(16) unsigned short Bs[64 * 72];
    const int bid = blockIdx.x;
    const int mt = bid >> 3, nt = bid & 7;
    gemm32<1>(aout, WoT, nullptr, out, mt * 32, nt * 64, 1024, 1024, 512,
              512, 8, As, Bs);
}

// ---------------- launch ----------------------------------------------------

extern "C" void kernel_launch(void* const* d_in, const int* in_sizes, int n_in,
                              void* d_out, int out_size, void* d_ws, size_t ws_size,
                              hipStream_t stream) {
    const float* query = (const float*)d_in[0];
    const float* src   = (const float*)d_in[1];
    const float* trg   = (const float*)d_in[2];
    const float* Wq    = (const float*)d_in[3];
    const float* bq    = (const float*)d_in[4];
    const float* Ws    = (const float*)d_in[5];
    const float* bs    = (const float*)d_in[6];
    const float* Wo    = (const float*)d_in[7];
    const float* bo    = (const float*)d_in[8];
    float* out = (float*)d_out;

    float* keys = (float*)d_ws;               // 1600*512
    float* sc   = keys + 819200;              // 1024*256
    unsigned short* qh  = (unsigned short*)(sc + 262144);  // q hidden bf16 1024x512
    unsigned short* abf = qh  + 524288;       // [src;trg] 1600x2048
    unsigned short* aout= abf + 3276800;      // [query,ctx] 1024x1024
    unsigned short* wqt = aout + 1048576;     // WqT 512x512
    unsigned short* wst = wqt  + 262144;      // WsT 512x2048
    unsigned short* wot = wst  + 1048576;     // WoT 512x1024

    k_prep<<<6304, 256, 0, stream>>>(query, src, trg, Wq, Ws, Wo, bs,
                                     aout, abf, wqt, wst, wot, keys);
    k_stageB<<<912, 256, 0, stream>>>(aout, abf, wqt, wst, wot, bq, bo,
                                      qh, keys, out);
    k_scgemm<<<128, 256, 0, stream>>>(qh, keys, sc);
    k_ctx<<<dim3(16, 8, 4), 256, 0, stream>>>(sc, keys, aout);
    k_out<<<256, 256, 0, stream>>>(aout, wot, out);
}